// Round 15
// baseline (667.366 us; speedup 1.0000x reference)
//
#include <hip/hip_runtime.h>

#define IN_F 4096
#define OUT_F 4096
#define NROWS 8192   // 4*2048
#define BK 32
#define NT (IN_F / BK)   // 128

typedef __attribute__((ext_vector_type(4))) float f32x4;
typedef __attribute__((ext_vector_type(8))) short bf16x8;
typedef __attribute__((ext_vector_type(8))) unsigned short u16x8;

__device__ __forceinline__ unsigned short f2bf(float f) {
  union { float f; unsigned u; } x; x.f = f;
  unsigned r = x.u + 0x7FFFu + ((x.u >> 16) & 1u);   // RNE
  return (unsigned short)(r >> 16);
}

__device__ __forceinline__ void gload_lds16(const unsigned short* g, unsigned short* l) {
  __builtin_amdgcn_global_load_lds((__attribute__((address_space(1))) void*)g,
                                   (__attribute__((address_space(3))) void*)l,
                                   16, 0, 0);
}

// in-register 16-point FWHT (4 butterfly bits)
__device__ __forceinline__ void bfly16(float v[16]) {
#pragma unroll
  for (int s = 1; s < 16; s <<= 1) {
#pragma unroll
    for (int i = 0; i < 16; ++i) {
      if (!(i & s)) { float a = v[i], b = v[i + s]; v[i] = a + b; v[i + s] = a - b; }
    }
  }
}

// ---------------- 1) dequant ----------------
__global__ __launch_bounds__(256) void dequant_kernel(const int* __restrict__ Q,
                                                      const float* __restrict__ grid,
                                                      unsigned short* __restrict__ Wb) {
  int g = blockIdx.x * 256 + threadIdx.x;
  int idx = Q[g];
  const f32x4* gp = (const f32x4*)(grid + idx * 8);
  f32x4 v0 = gp[0], v1 = gp[1];
  u16x8 o;
  o[0] = f2bf(v0[0]); o[1] = f2bf(v0[1]); o[2] = f2bf(v0[2]); o[3] = f2bf(v0[3]);
  o[4] = f2bf(v1[0]); o[5] = f2bf(v1[1]); o[6] = f2bf(v1[2]); o[7] = f2bf(v1[3]);
  *(u16x8*)(Wb + (size_t)g * 8) = o;
}

// ---------------- 2) fwht1: H = fwht(x*SU) -> bf16 ----------------
__global__ __launch_bounds__(256) void fwht1_kernel(const float* __restrict__ x,
                                                    const float* __restrict__ SU,
                                                    unsigned short* __restrict__ Hb) {
  __shared__ float buf[4096];
  int tid = threadIdx.x;
  size_t rbase = (size_t)blockIdx.x * IN_F;
  const f32x4* x4 = (const f32x4*)(x + rbase);
  const f32x4* su4 = (const f32x4*)SU;
  f32x4* b4 = (f32x4*)buf;
#pragma unroll
  for (int s = 0; s < 4; ++s) {
    int c = tid + 256 * s;
    f32x4 v = x4[c];
    f32x4 u = su4[c];
    v.x *= u.x; v.y *= u.y; v.z *= u.z; v.w *= u.w;
    b4[c] = v;
  }
  __syncthreads();
  float v[16];
  {
#pragma unroll
    for (int j = 0; j < 4; ++j) {
      f32x4 t4 = b4[tid * 4 + j];
      v[j*4+0] = t4.x; v[j*4+1] = t4.y; v[j*4+2] = t4.z; v[j*4+3] = t4.w;
    }
    bfly16(v);
#pragma unroll
    for (int j = 0; j < 4; ++j) {
      f32x4 t4; t4.x = v[j*4+0]; t4.y = v[j*4+1]; t4.z = v[j*4+2]; t4.w = v[j*4+3];
      b4[tid * 4 + j] = t4;
    }
  }
  __syncthreads();
  {
    int lo = tid & 15, hi = tid >> 4;
    int base = lo + (hi << 8);
#pragma unroll
    for (int j = 0; j < 16; ++j) v[j] = buf[base + (j << 4)];
    bfly16(v);
#pragma unroll
    for (int j = 0; j < 16; ++j) buf[base + (j << 4)] = v[j];
  }
  __syncthreads();
  {
#pragma unroll
    for (int j = 0; j < 16; ++j) v[j] = buf[tid + (j << 8)];
    bfly16(v);
#pragma unroll
    for (int j = 0; j < 16; ++j)
      Hb[rbase + tid + (j << 8)] = f2bf(v[j] * 0.015625f);   // 1/sqrt(4096)
  }
}

// ---------------- 3) GEMM 256x256, 8 waves x (128x64), A via GLOBAL->VGPR, B via LDS ----------------
// A-fragments load straight from global (16 rows x 64B contiguous segments per
// instruction, perfectly coalesced; L1/L2-served with 4-way wave reuse), so LDS
// traffic/tile drops 1540->~575 cy < MFMA 1242 cy.  B keeps the r3-verified
// 0-conflict LDS path (ring-4, 64 KiB).  Compiler inserts precise counted vmcnt
// for the A-loads; manual vmcnt(2) guards B staging residency.
__global__ __launch_bounds__(512) void gemm256_kernel(const unsigned short* __restrict__ Hb,
                                                      const unsigned short* __restrict__ Wb,
                                                      float* __restrict__ Y) {
  __shared__ unsigned short lds[4][256 * BK];   // B ring-4 x 16KB = 64 KiB
  const int tid = threadIdx.x;
  const int lane = tid & 63;
  const int wid = tid >> 6;        // 0..7
  const int wr = wid >> 2;         // 0..1  (M half)
  const int wc = wid & 3;          // 0..3  (N quarter)
  const int lrow = lane & 15;
  const int kgrp = lane >> 4;

  const int bid = blockIdx.x;
  const int swz = (bid & 7) * 64 + (bid >> 3);     // nwg=512, bijective XCD swizzle
  const int brow = (swz >> 4) << 8;
  const int bcol = (swz & 15) << 8;

  // B staging: 2 gloads/thread/tile (rows r0, r0+128); bank swizzle on GLOBAL
  // source (r3-verified 0-conflict); LDS dest lane-linear (gload requirement).
  const int r0 = tid >> 2;
  const int sc = ((tid & 3) ^ ((r0 >> 1) & 3)) << 3;
  const unsigned short* BgR0 = Wb + (size_t)(bcol + r0) * IN_F + sc;
  const unsigned short* BgR1 = Wb + (size_t)(bcol + r0 + 128) * IN_F + sc;

#define STAGE_B(t) { \
  gload_lds16(BgR0 + (t) * BK, &lds[(t) & 3][tid * 8]); \
  gload_lds16(BgR1 + (t) * BK, &lds[(t) & 3][(tid + 512) * 8]); }

  auto fragLd = [&](const unsigned short* base, int R) -> bf16x8 {
    return *(const bf16x8*)(base + R * BK + ((kgrp ^ ((R >> 1) & 3)) << 3));
  };

  const int br = wc * 64 + lrow;

#define READ_B(t) { const unsigned short* Bs_ = &lds[(t) & 3][0]; \
  b0 = fragLd(Bs_, br +  0); b1 = fragLd(Bs_, br + 16); \
  b2 = fragLd(Bs_, br + 32); b3 = fragLd(Bs_, br + 48); }

  // A direct: lane reads A[brow + wr*128 + m*16 + lrow][t*32 + kgrp*8 .. +8]
  const unsigned short* pA = Hb + (size_t)(brow + wr * 128 + lrow) * IN_F + kgrp * 8;

#define LOAD_A(t, aS) { \
  _Pragma("unroll") \
  for (int m = 0; m < 8; ++m) \
    aS[m] = *(const bf16x8*)(pA + (size_t)m * 16 * IN_F + (t) * BK); }

#define MM(i, A, B) acc[i] = __builtin_amdgcn_mfma_f32_16x16x32_bf16(A, B, acc[i], 0, 0, 0)
#define MMROW(m, aS) { \
  MM((m)*4+0, aS[m], b0); MM((m)*4+1, aS[m], b1); \
  MM((m)*4+2, aS[m], b2); MM((m)*4+3, aS[m], b3); }

  // tile t: manual vmcnt(2) retires everything except sB(t+2) -> B(t+1) resident;
  // compiler guards aCur's RAW with its own counted vmcnt before the MFMAs.
#define TILE_BODY(t, aCur, aNxt) { \
  if ((t) + 2 < NT) { asm volatile("s_waitcnt vmcnt(2)" ::: "memory"); } \
  else              { asm volatile("s_waitcnt vmcnt(0)" ::: "memory"); } \
  __builtin_amdgcn_s_barrier(); \
  READ_B(t); \
  if ((t) + 1 < NT) LOAD_A((t) + 1, aNxt); \
  if ((t) + 3 < NT) STAGE_B((t) + 3); \
  asm volatile("s_waitcnt lgkmcnt(0)" ::: "memory"); \
  __builtin_amdgcn_sched_barrier(0); \
  __builtin_amdgcn_s_setprio(1); \
  MMROW(0, aCur); MMROW(1, aCur); MMROW(2, aCur); MMROW(3, aCur); \
  MMROW(4, aCur); MMROW(5, aCur); MMROW(6, aCur); MMROW(7, aCur); \
  __builtin_amdgcn_s_setprio(0); }

  f32x4 acc[32] = {};
  bf16x8 aC[8], aN[8], b0, b1, b2, b3;

  // prologue: stage B tiles 0,1,2; load A tile0; one-time full drain
  STAGE_B(0); STAGE_B(1); STAGE_B(2);
  LOAD_A(0, aC);
  asm volatile("s_waitcnt vmcnt(0)" ::: "memory");
  __builtin_amdgcn_s_barrier();

  for (int t = 0; t < NT; t += 2) {
    TILE_BODY(t,     aC, aN);
    TILE_BODY(t + 1, aN, aC);
  }

  // epilogue: C/D layout col=lane&15 (B side), row=kgrp*4+r (A side)
#pragma unroll
  for (int mf = 0; mf < 8; ++mf) {
    int grow = brow + wr * 128 + mf * 16 + kgrp * 4;
    float* yp = Y + (size_t)grow * OUT_F + bcol + wc * 64 + lrow;
#pragma unroll
    for (int r = 0; r < 4; ++r)
#pragma unroll
      for (int nf = 0; nf < 4; ++nf)
        yp[(size_t)r * OUT_F + nf * 16] = acc[mf * 4 + nf][r];
  }
#undef STAGE_B
#undef READ_B
#undef LOAD_A
#undef MM
#undef MMROW
#undef TILE_BODY
}

// ---------------- 4) fwht2 (in-place on d_out) + SV + bias ----------------
__global__ __launch_bounds__(256) void fwht2_kernel(float* __restrict__ Y,
                                                    const float* __restrict__ SV,
                                                    const float* __restrict__ bias) {
  __shared__ float buf[4096];
  int tid = threadIdx.x;
  size_t rbase = (size_t)blockIdx.x * OUT_F;
  f32x4* y4 = (f32x4*)(Y + rbase);
  f32x4* b4 = (f32x4*)buf;
#pragma unroll
  for (int s = 0; s < 4; ++s) {
    int c = tid + 256 * s;
    b4[c] = y4[c];
  }
  __syncthreads();
  float v[16];
  {
#pragma unroll
    for (int j = 0; j < 4; ++j) {
      f32x4 t4 = b4[tid * 4 + j];
      v[j*4+0] = t4.x; v[j*4+1] = t4.y; v[j*4+2] = t4.z; v[j*4+3] = t4.w;
    }
    bfly16(v);
#pragma unroll
    for (int j = 0; j < 4; ++j) {
      f32x4 t4; t4.x = v[j*4+0]; t4.y = v[j*4+1]; t4.z = v[j*4+2]; t4.w = v[j*4+3];
      b4[tid * 4 + j] = t4;
    }
  }
  __syncthreads();
  {
    int lo = tid & 15, hi = tid >> 4;
    int base = lo + (hi << 8);
#pragma unroll
    for (int j = 0; j < 16; ++j) v[j] = buf[base + (j << 4)];
    bfly16(v);
#pragma unroll
    for (int j = 0; j < 16; ++j) buf[base + (j << 4)] = v[j];
  }
  __syncthreads();
  {
#pragma unroll
    for (int j = 0; j < 16; ++j) v[j] = buf[tid + (j << 8)];
    bfly16(v);
#pragma unroll
    for (int j = 0; j < 16; ++j) {
      int col = tid + (j << 8);
      Y[rbase + col] = v[j] * 0.015625f * SV[col] + bias[col];
    }
  }
}

extern "C" void kernel_launch(void* const* d_in, const int* in_sizes, int n_in,
                              void* d_out, int out_size, void* d_ws, size_t ws_size,
                              hipStream_t stream) {
  const float* x     = (const float*)d_in[0];
  const int*   Qidxs = (const int*)d_in[1];
  const float* grid  = (const float*)d_in[2];
  const float* SU    = (const float*)d_in[3];
  const float* SV    = (const float*)d_in[4];
  const float* bias  = (const float*)d_in[5];
  float* out = (float*)d_out;

  unsigned short* Wb = (unsigned short*)d_ws;                    // 4096*4096 bf16 = 33.5 MB
  unsigned short* Hb = Wb + (size_t)OUT_F * IN_F;                // 8192*4096 bf16 = 67 MB

  hipLaunchKernelGGL(dequant_kernel, dim3((OUT_F * (IN_F / 8)) / 256), dim3(256), 0, stream,
                     Qidxs, grid, Wb);
  hipLaunchKernelGGL(fwht1_kernel, dim3(NROWS), dim3(256), 0, stream, x, SU, Hb);
  hipLaunchKernelGGL(gemm256_kernel, dim3((NROWS / 256) * (OUT_F / 256)), dim3(512), 0, stream,
                     Hb, Wb, out);
  hipLaunchKernelGGL(fwht2_kernel, dim3(NROWS), dim3(256), 0, stream, out, SV, bias);
}

// Round 16
// 606.819 us; speedup vs baseline: 1.0998x; 1.0998x over previous
//
#include <hip/hip_runtime.h>

#define IN_F 4096
#define OUT_F 4096
#define NROWS 8192   // 4*2048
#define BK 32
#define NT (IN_F / BK)   // 128

typedef __attribute__((ext_vector_type(4))) float f32x4;
typedef __attribute__((ext_vector_type(8))) short bf16x8;
typedef __attribute__((ext_vector_type(8))) unsigned short u16x8;

__device__ __forceinline__ unsigned short f2bf(float f) {
  union { float f; unsigned u; } x; x.f = f;
  unsigned r = x.u + 0x7FFFu + ((x.u >> 16) & 1u);   // RNE
  return (unsigned short)(r >> 16);
}

__device__ __forceinline__ void gload_lds16(const unsigned short* g, unsigned short* l) {
  __builtin_amdgcn_global_load_lds((__attribute__((address_space(1))) void*)g,
                                   (__attribute__((address_space(3))) void*)l,
                                   16, 0, 0);
}

// in-register 16-point FWHT (4 butterfly bits)
__device__ __forceinline__ void bfly16(float v[16]) {
#pragma unroll
  for (int s = 1; s < 16; s <<= 1) {
#pragma unroll
    for (int i = 0; i < 16; ++i) {
      if (!(i & s)) { float a = v[i], b = v[i + s]; v[i] = a + b; v[i + s] = a - b; }
    }
  }
}

// ---------------- 1) dequant ----------------
__global__ __launch_bounds__(256) void dequant_kernel(const int* __restrict__ Q,
                                                      const float* __restrict__ grid,
                                                      unsigned short* __restrict__ Wb) {
  int g = blockIdx.x * 256 + threadIdx.x;
  int idx = Q[g];
  const f32x4* gp = (const f32x4*)(grid + idx * 8);
  f32x4 v0 = gp[0], v1 = gp[1];
  u16x8 o;
  o[0] = f2bf(v0[0]); o[1] = f2bf(v0[1]); o[2] = f2bf(v0[2]); o[3] = f2bf(v0[3]);
  o[4] = f2bf(v1[0]); o[5] = f2bf(v1[1]); o[6] = f2bf(v1[2]); o[7] = f2bf(v1[3]);
  *(u16x8*)(Wb + (size_t)g * 8) = o;
}

// ---------------- 2) fwht1: H = fwht(x*SU) -> bf16 ----------------
__global__ __launch_bounds__(256) void fwht1_kernel(const float* __restrict__ x,
                                                    const float* __restrict__ SU,
                                                    unsigned short* __restrict__ Hb) {
  __shared__ float buf[4096];
  int tid = threadIdx.x;
  size_t rbase = (size_t)blockIdx.x * IN_F;
  const f32x4* x4 = (const f32x4*)(x + rbase);
  const f32x4* su4 = (const f32x4*)SU;
  f32x4* b4 = (f32x4*)buf;
#pragma unroll
  for (int s = 0; s < 4; ++s) {
    int c = tid + 256 * s;
    f32x4 v = x4[c];
    f32x4 u = su4[c];
    v.x *= u.x; v.y *= u.y; v.z *= u.z; v.w *= u.w;
    b4[c] = v;
  }
  __syncthreads();
  float v[16];
  {
#pragma unroll
    for (int j = 0; j < 4; ++j) {
      f32x4 t4 = b4[tid * 4 + j];
      v[j*4+0] = t4.x; v[j*4+1] = t4.y; v[j*4+2] = t4.z; v[j*4+3] = t4.w;
    }
    bfly16(v);
#pragma unroll
    for (int j = 0; j < 4; ++j) {
      f32x4 t4; t4.x = v[j*4+0]; t4.y = v[j*4+1]; t4.z = v[j*4+2]; t4.w = v[j*4+3];
      b4[tid * 4 + j] = t4;
    }
  }
  __syncthreads();
  {
    int lo = tid & 15, hi = tid >> 4;
    int base = lo + (hi << 8);
#pragma unroll
    for (int j = 0; j < 16; ++j) v[j] = buf[base + (j << 4)];
    bfly16(v);
#pragma unroll
    for (int j = 0; j < 16; ++j) buf[base + (j << 4)] = v[j];
  }
  __syncthreads();
  {
#pragma unroll
    for (int j = 0; j < 16; ++j) v[j] = buf[tid + (j << 8)];
    bfly16(v);
#pragma unroll
    for (int j = 0; j < 16; ++j)
      Hb[rbase + tid + (j << 8)] = f2bf(v[j] * 0.015625f);   // 1/sqrt(4096)
  }
}

// ---------------- 3) GEMM: 128x256 block, 4 waves x (128x64), ring-3, 2 blocks/CU ----------------
// Cross-block desync (m114): two co-resident blocks with independent barriers
// overlap one block's LDS reads with the other's MFMA bursts — the overlap all
// single-block schedules failed to get.  72 KiB LDS -> 2 blocks/CU.  All pieces
// (swizzle, fragLd, epilogue, counted vmcnt) are r3/r9/r11-verified.
__global__ __launch_bounds__(256) void gemm_kernel(const unsigned short* __restrict__ Hb,
                                                   const unsigned short* __restrict__ Wb,
                                                   float* __restrict__ Y) {
  __shared__ unsigned short ldsA[3][128 * BK];   // 3 x 8 KB
  __shared__ unsigned short ldsB[3][256 * BK];   // 3 x 16 KB   (total 72 KiB)
  const int tid = threadIdx.x;
  const int lane = tid & 63;
  const int wid = tid >> 6;        // 0..3  (N quarter)
  const int lrow = lane & 15;
  const int kgrp = lane >> 4;

  const int bid = blockIdx.x;
  const int swz = (bid & 7) * 128 + (bid >> 3);   // nwg=1024 (%8==0), bijective
  const int brow = (swz >> 4) << 7;               // 64 M-blocks x 128
  const int bcol = (swz & 15) << 8;               // 16 N-blocks x 256

  // staging: A 2 chunks/thread (rows r0, r0+64), B 4 chunks/thread (r0+64i);
  // bank swizzle on GLOBAL source (r3-verified 0-conflict); LDS dest lane-linear.
  const int r0 = tid >> 2;                        // 0..63
  const int sc = ((tid & 3) ^ ((r0 >> 1) & 3)) << 3;
  const unsigned short* AgR0 = Hb + (size_t)(brow + r0) * IN_F + sc;
  const unsigned short* AgR1 = Hb + (size_t)(brow + r0 + 64) * IN_F + sc;
  const unsigned short* BgR0 = Wb + (size_t)(bcol + r0) * IN_F + sc;
  const unsigned short* BgR1 = Wb + (size_t)(bcol + r0 + 64) * IN_F + sc;
  const unsigned short* BgR2 = Wb + (size_t)(bcol + r0 + 128) * IN_F + sc;
  const unsigned short* BgR3 = Wb + (size_t)(bcol + r0 + 192) * IN_F + sc;

#define STAGE(t) { int sl_ = (t) % 3; \
  gload_lds16(AgR0 + (t) * BK, &ldsA[sl_][tid * 8]); \
  gload_lds16(AgR1 + (t) * BK, &ldsA[sl_][(tid + 256) * 8]); \
  gload_lds16(BgR0 + (t) * BK, &ldsB[sl_][tid * 8]); \
  gload_lds16(BgR1 + (t) * BK, &ldsB[sl_][(tid + 256) * 8]); \
  gload_lds16(BgR2 + (t) * BK, &ldsB[sl_][(tid + 512) * 8]); \
  gload_lds16(BgR3 + (t) * BK, &ldsB[sl_][(tid + 768) * 8]); }

  auto fragLd = [&](const unsigned short* base, int R) -> bf16x8 {
    return *(const bf16x8*)(base + R * BK + ((kgrp ^ ((R >> 1) & 3)) << 3));
  };

  const int ar = lrow;                 // wave covers all 128 A-rows
  const int br = wid * 64 + lrow;      // wave's 64 B-rows

#define MM(i, A, B) acc[i] = __builtin_amdgcn_mfma_f32_16x16x32_bf16(A, B, acc[i], 0, 0, 0)
#define MMROW(m) { \
  MM((m)*4+0, a[m], b0); MM((m)*4+1, a[m], b1); \
  MM((m)*4+2, a[m], b2); MM((m)*4+3, a[m], b3); }

  f32x4 acc[32] = {};
  bf16x8 a[8], b0, b1, b2, b3;

  // prologue: stage tiles 0,1 (12 loads); vmcnt(6) retires S0
  STAGE(0); STAGE(1);
  asm volatile("s_waitcnt vmcnt(6)" ::: "memory");
  __builtin_amdgcn_s_barrier();

  for (int t = 0; t < NT; ++t) {
    const int sl = t % 3;
    const unsigned short* As = &ldsA[sl][0];
    const unsigned short* Bs = &ldsB[sl][0];

    if (t + 2 < NT) STAGE(t + 2);
    // frag reads for tile t (S(t) resident: fenced by vmcnt at previous tile end)
    b0 = fragLd(Bs, br +  0); b1 = fragLd(Bs, br + 16);
    b2 = fragLd(Bs, br + 32); b3 = fragLd(Bs, br + 48);
    a[0] = fragLd(As,  0 + ar); a[1] = fragLd(As, 16 + ar);
    a[2] = fragLd(As, 32 + ar); a[3] = fragLd(As, 48 + ar);
    a[4] = fragLd(As, 64 + ar); a[5] = fragLd(As, 80 + ar);
    a[6] = fragLd(As, 96 + ar); a[7] = fragLd(As, 112 + ar);
    asm volatile("s_waitcnt lgkmcnt(0)" ::: "memory");
    __builtin_amdgcn_sched_barrier(0);
    __builtin_amdgcn_s_setprio(1);
    MMROW(0); MMROW(1); MMROW(2); MMROW(3);
    MMROW(4); MMROW(5); MMROW(6); MMROW(7);
    __builtin_amdgcn_s_setprio(0);
    // tile end: ensure S(t+1) retired before tile t+1 reads it.
    // outstanding here: S(t+1) (6) + S(t+2) (6, just issued) -> vmcnt(6).
    if (t + 2 < NT)      { asm volatile("s_waitcnt vmcnt(6)" ::: "memory"); }
    else                 { asm volatile("s_waitcnt vmcnt(0)" ::: "memory"); }
    __builtin_amdgcn_s_barrier();
  }

  // epilogue: C/D layout col=lane&15 (B side), row=kgrp*4+r (A side)
#pragma unroll
  for (int mf = 0; mf < 8; ++mf) {
    int grow = brow + mf * 16 + kgrp * 4;
    float* yp = Y + (size_t)grow * OUT_F + bcol + wid * 64 + lrow;
#pragma unroll
    for (int r = 0; r < 4; ++r)
#pragma unroll
      for (int nf = 0; nf < 4; ++nf)
        yp[(size_t)r * OUT_F + nf * 16] = acc[mf * 4 + nf][r];
  }
#undef STAGE
#undef MM
#undef MMROW
}

// ---------------- 4) fwht2 (in-place on d_out) + SV + bias ----------------
__global__ __launch_bounds__(256) void fwht2_kernel(float* __restrict__ Y,
                                                    const float* __restrict__ SV,
                                                    const float* __restrict__ bias) {
  __shared__ float buf[4096];
  int tid = threadIdx.x;
  size_t rbase = (size_t)blockIdx.x * OUT_F;
  f32x4* y4 = (f32x4*)(Y + rbase);
  f32x4* b4 = (f32x4*)buf;
#pragma unroll
  for (int s = 0; s < 4; ++s) {
    int c = tid + 256 * s;
    b4[c] = y4[c];
  }
  __syncthreads();
  float v[16];
  {
#pragma unroll
    for (int j = 0; j < 4; ++j) {
      f32x4 t4 = b4[tid * 4 + j];
      v[j*4+0] = t4.x; v[j*4+1] = t4.y; v[j*4+2] = t4.z; v[j*4+3] = t4.w;
    }
    bfly16(v);
#pragma unroll
    for (int j = 0; j < 4; ++j) {
      f32x4 t4; t4.x = v[j*4+0]; t4.y = v[j*4+1]; t4.z = v[j*4+2]; t4.w = v[j*4+3];
      b4[tid * 4 + j] = t4;
    }
  }
  __syncthreads();
  {
    int lo = tid & 15, hi = tid >> 4;
    int base = lo + (hi << 8);
#pragma unroll
    for (int j = 0; j < 16; ++j) v[j] = buf[base + (j << 4)];
    bfly16(v);
#pragma unroll
    for (int j = 0; j < 16; ++j) buf[base + (j << 4)] = v[j];
  }
  __syncthreads();
  {
#pragma unroll
    for (int j = 0; j < 16; ++j) v[j] = buf[tid + (j << 8)];
    bfly16(v);
#pragma unroll
    for (int j = 0; j < 16; ++j) {
      int col = tid + (j << 8);
      Y[rbase + col] = v[j] * 0.015625f * SV[col] + bias[col];
    }
  }
}

extern "C" void kernel_launch(void* const* d_in, const int* in_sizes, int n_in,
                              void* d_out, int out_size, void* d_ws, size_t ws_size,
                              hipStream_t stream) {
  const float* x     = (const float*)d_in[0];
  const int*   Qidxs = (const int*)d_in[1];
  const float* grid  = (const float*)d_in[2];
  const float* SU    = (const float*)d_in[3];
  const float* SV    = (const float*)d_in[4];
  const float* bias  = (const float*)d_in[5];
  float* out = (float*)d_out;

  unsigned short* Wb = (unsigned short*)d_ws;                    // 4096*4096 bf16 = 33.5 MB
  unsigned short* Hb = Wb + (size_t)OUT_F * IN_F;                // 8192*4096 bf16 = 67 MB

  hipLaunchKernelGGL(dequant_kernel, dim3((OUT_F * (IN_F / 8)) / 256), dim3(256), 0, stream,
                     Qidxs, grid, Wb);
  hipLaunchKernelGGL(fwht1_kernel, dim3(NROWS), dim3(256), 0, stream, x, SU, Hb);
  hipLaunchKernelGGL(gemm_kernel, dim3((NROWS / 128) * (OUT_F / 256)), dim3(256), 0, stream,
                     Hb, Wb, out);
  hipLaunchKernelGGL(fwht2_kernel, dim3(NROWS), dim3(256), 0, stream, out, SV, bias);
}

// Round 17
// 325.816 us; speedup vs baseline: 2.0483x; 1.8625x over previous
//
#include <hip/hip_runtime.h>

#define IN_F 4096
#define OUT_F 4096
#define NROWS 8192   // 4*2048
#define NT 64        // K64-tiles

typedef __attribute__((ext_vector_type(4))) float f32x4;
typedef __attribute__((ext_vector_type(8))) short bf16x8;
typedef __attribute__((ext_vector_type(8))) unsigned short u16x8;

__device__ __forceinline__ unsigned short f2bf(float f) {
  union { float f; unsigned u; } x; x.f = f;
  unsigned r = x.u + 0x7FFFu + ((x.u >> 16) & 1u);   // RNE
  return (unsigned short)(r >> 16);
}

__device__ __forceinline__ void gload_lds16(const unsigned short* g, unsigned short* l) {
  __builtin_amdgcn_global_load_lds((__attribute__((address_space(1))) void*)g,
                                   (__attribute__((address_space(3))) void*)l,
                                   16, 0, 0);
}

// in-register 16-point FWHT (4 butterfly bits)
__device__ __forceinline__ void bfly16(float v[16]) {
#pragma unroll
  for (int s = 1; s < 16; s <<= 1) {
#pragma unroll
    for (int i = 0; i < 16; ++i) {
      if (!(i & s)) { float a = v[i], b = v[i + s]; v[i] = a + b; v[i + s] = a - b; }
    }
  }
}

// ---------------- 1) dequant ----------------
__global__ __launch_bounds__(256) void dequant_kernel(const int* __restrict__ Q,
                                                      const float* __restrict__ grid,
                                                      unsigned short* __restrict__ Wb) {
  int g = blockIdx.x * 256 + threadIdx.x;
  int idx = Q[g];
  const f32x4* gp = (const f32x4*)(grid + idx * 8);
  f32x4 v0 = gp[0], v1 = gp[1];
  u16x8 o;
  o[0] = f2bf(v0[0]); o[1] = f2bf(v0[1]); o[2] = f2bf(v0[2]); o[3] = f2bf(v0[3]);
  o[4] = f2bf(v1[0]); o[5] = f2bf(v1[1]); o[6] = f2bf(v1[2]); o[7] = f2bf(v1[3]);
  *(u16x8*)(Wb + (size_t)g * 8) = o;
}

// ---------------- 2) fwht1: H = fwht(x*SU) -> bf16 ----------------
__global__ __launch_bounds__(256) void fwht1_kernel(const float* __restrict__ x,
                                                    const float* __restrict__ SU,
                                                    unsigned short* __restrict__ Hb) {
  __shared__ float buf[4096];
  int tid = threadIdx.x;
  size_t rbase = (size_t)blockIdx.x * IN_F;
  const f32x4* x4 = (const f32x4*)(x + rbase);
  const f32x4* su4 = (const f32x4*)SU;
  f32x4* b4 = (f32x4*)buf;
#pragma unroll
  for (int s = 0; s < 4; ++s) {
    int c = tid + 256 * s;
    f32x4 v = x4[c];
    f32x4 u = su4[c];
    v.x *= u.x; v.y *= u.y; v.z *= u.z; v.w *= u.w;
    b4[c] = v;
  }
  __syncthreads();
  float v[16];
  {
#pragma unroll
    for (int j = 0; j < 4; ++j) {
      f32x4 t4 = b4[tid * 4 + j];
      v[j*4+0] = t4.x; v[j*4+1] = t4.y; v[j*4+2] = t4.z; v[j*4+3] = t4.w;
    }
    bfly16(v);
#pragma unroll
    for (int j = 0; j < 4; ++j) {
      f32x4 t4; t4.x = v[j*4+0]; t4.y = v[j*4+1]; t4.z = v[j*4+2]; t4.w = v[j*4+3];
      b4[tid * 4 + j] = t4;
    }
  }
  __syncthreads();
  {
    int lo = tid & 15, hi = tid >> 4;
    int base = lo + (hi << 8);
#pragma unroll
    for (int j = 0; j < 16; ++j) v[j] = buf[base + (j << 4)];
    bfly16(v);
#pragma unroll
    for (int j = 0; j < 16; ++j) buf[base + (j << 4)] = v[j];
  }
  __syncthreads();
  {
#pragma unroll
    for (int j = 0; j < 16; ++j) v[j] = buf[tid + (j << 8)];
    bfly16(v);
#pragma unroll
    for (int j = 0; j < 16; ++j)
      Hb[rbase + tid + (j << 8)] = f2bf(v[j] * 0.015625f);   // 1/sqrt(4096)
  }
}

// ---------------- 3) GEMM 256x256, 8 waves x (128x64), BK=64 (2 k-halves),
// 4 uniform phases/tile {4-8 ds_read; 1 half-stage; bar; lgkm0; 16 MFMA; bar},
// counted vmcnt(8) with 5-6 phases of prefetch slack (m201 regime).
// Best-measured configuration of the session (r9: gemm ~250us, total 326.5us).
__global__ __launch_bounds__(512) void gemm256_kernel(const unsigned short* __restrict__ Hb,
                                                      const unsigned short* __restrict__ Wb,
                                                      float* __restrict__ Y) {
  __shared__ unsigned short lds[2][2][2][256 * 32];  // [slot][A,B][khalf][row*32] = 128 KiB
  const int tid = threadIdx.x;
  const int lane = tid & 63;
  const int wid = tid >> 6;        // 0..7
  const int wr = wid >> 2;         // 0..1  (M half)
  const int wc = wid & 3;          // 0..3  (N quarter)
  const int lrow = lane & 15;
  const int kgrp = lane >> 4;

  const int bid = blockIdx.x;
  const int swz = (bid & 7) * 64 + (bid >> 3);     // nwg=512, bijective XCD swizzle
  const int brow = (swz >> 4) << 8;
  const int bcol = (swz & 15) << 8;

  // staging: per half-unit (one array, one khalf: 256 rows x 32 k = 16KB) each
  // thread issues 2 gloads (rows r0, r0+128). Bank swizzle on GLOBAL source
  // within the 4 16B-slots of a 32-elem k-half (r3-verified: 0 conflicts).
  const int r0 = tid >> 2;
  const int sc = ((tid & 3) ^ ((r0 >> 1) & 3)) << 3;
  const unsigned short* AgR0 = Hb + (size_t)(brow + r0) * IN_F + sc;
  const unsigned short* AgR1 = Hb + (size_t)(brow + r0 + 128) * IN_F + sc;
  const unsigned short* BgR0 = Wb + (size_t)(bcol + r0) * IN_F + sc;
  const unsigned short* BgR1 = Wb + (size_t)(bcol + r0 + 128) * IN_F + sc;

  // dest lane-linear: row*32 + (tid&3)*8 == tid*8  (wave base w*512) -> gload-valid
#define STAGE_A(t, kk) { \
  gload_lds16(AgR0 + (t) * 64 + (kk) * 32, &lds[(t) & 1][0][kk][tid * 8]); \
  gload_lds16(AgR1 + (t) * 64 + (kk) * 32, &lds[(t) & 1][0][kk][(tid + 512) * 8]); }
#define STAGE_B(t, kk) { \
  gload_lds16(BgR0 + (t) * 64 + (kk) * 32, &lds[(t) & 1][1][kk][tid * 8]); \
  gload_lds16(BgR1 + (t) * 64 + (kk) * 32, &lds[(t) & 1][1][kk][(tid + 512) * 8]); }

  auto fragLd = [&](const unsigned short* base, int R) -> bf16x8 {
    return *(const bf16x8*)(base + R * 32 + ((kgrp ^ ((R >> 1) & 3)) << 3));
  };

  const int ar = wr * 128 + lrow;
  const int br = wc * 64 + lrow;

#define MM(i, A, B) acc[i] = __builtin_amdgcn_mfma_f32_16x16x32_bf16(A, B, acc[i], 0, 0, 0)
#define BURST(base) { \
  asm volatile("s_waitcnt lgkmcnt(0)" ::: "memory"); \
  __builtin_amdgcn_sched_barrier(0); \
  __builtin_amdgcn_s_setprio(1); \
  MM((base)+ 0, a0, b0); MM((base)+ 1, a0, b1); MM((base)+ 2, a0, b2); MM((base)+ 3, a0, b3); \
  MM((base)+ 4, a1, b0); MM((base)+ 5, a1, b1); MM((base)+ 6, a1, b2); MM((base)+ 7, a1, b3); \
  MM((base)+ 8, a2, b0); MM((base)+ 9, a2, b1); MM((base)+10, a2, b2); MM((base)+11, a2, b3); \
  MM((base)+12, a3, b0); MM((base)+13, a3, b1); MM((base)+14, a3, b2); MM((base)+15, a3, b3); \
  __builtin_amdgcn_s_setprio(0); }

  f32x4 acc[32] = {};
  bf16x8 a0, a1, a2, a3, b0, b1, b2, b3;

  // prologue: stage A0k0,B0k0,A0k1,B0k1,A1k0,B1k0 (12 loads); wait tile0-k0 resident
  STAGE_A(0, 0); STAGE_B(0, 0);
  STAGE_A(0, 1); STAGE_B(0, 1);
  STAGE_A(1, 0); STAGE_B(1, 0);
  asm volatile("s_waitcnt vmcnt(8)" ::: "memory");
  __builtin_amdgcn_s_barrier();

  for (int t = 0; t < NT; ++t) {
    const unsigned short* As0 = &lds[t & 1][0][0][0];
    const unsigned short* As1 = &lds[t & 1][0][1][0];
    const unsigned short* Bs0 = &lds[t & 1][1][0][0];
    const unsigned short* Bs1 = &lds[t & 1][1][1][0];

    // ---- P0: (h0, k0) — 8 reads ----
    a0 = fragLd(As0, ar +  0); a1 = fragLd(As0, ar + 16);
    a2 = fragLd(As0, ar + 32); a3 = fragLd(As0, ar + 48);
    b0 = fragLd(Bs0, br +  0); b1 = fragLd(Bs0, br + 16);
    b2 = fragLd(Bs0, br + 32); b3 = fragLd(Bs0, br + 48);
    if (t + 1 < NT) STAGE_A(t + 1, 1);
    __builtin_amdgcn_s_barrier();
    BURST(0);
    __builtin_amdgcn_s_barrier();

    // ---- P1: (h1, k0) — 4 reads (B k0 held) ----
    a0 = fragLd(As0, ar +  64); a1 = fragLd(As0, ar +  80);
    a2 = fragLd(As0, ar +  96); a3 = fragLd(As0, ar + 112);
    if (t + 1 < NT) STAGE_B(t + 1, 1);
    __builtin_amdgcn_s_barrier();
    BURST(16);
    if (t < NT - 1) { asm volatile("s_waitcnt vmcnt(8)" ::: "memory"); }
    else            { asm volatile("s_waitcnt vmcnt(0)" ::: "memory"); }
    __builtin_amdgcn_s_barrier();

    // ---- P2: (h0, k1) — 8 reads ----
    a0 = fragLd(As1, ar +  0); a1 = fragLd(As1, ar + 16);
    a2 = fragLd(As1, ar + 32); a3 = fragLd(As1, ar + 48);
    b0 = fragLd(Bs1, br +  0); b1 = fragLd(Bs1, br + 16);
    b2 = fragLd(Bs1, br + 32); b3 = fragLd(Bs1, br + 48);
    if (t + 2 < NT) STAGE_A(t + 2, 0);
    __builtin_amdgcn_s_barrier();
    BURST(0);
    __builtin_amdgcn_s_barrier();

    // ---- P3: (h1, k1) — 4 reads ----
    a0 = fragLd(As1, ar +  64); a1 = fragLd(As1, ar +  80);
    a2 = fragLd(As1, ar +  96); a3 = fragLd(As1, ar + 112);
    if (t + 2 < NT) STAGE_B(t + 2, 0);
    __builtin_amdgcn_s_barrier();
    BURST(16);
    if (t < NT - 2)       { asm volatile("s_waitcnt vmcnt(8)" ::: "memory"); }
    else if (t == NT - 2) { asm volatile("s_waitcnt vmcnt(4)" ::: "memory"); }
    else                  { asm volatile("s_waitcnt vmcnt(0)" ::: "memory"); }
    __builtin_amdgcn_s_barrier();
  }

  // epilogue: C/D layout col=lane&15 (B side), row=kgrp*4+r (A side)
#pragma unroll
  for (int mf = 0; mf < 8; ++mf) {
    int grow = brow + wr * 128 + mf * 16 + kgrp * 4;
    float* yp = Y + (size_t)grow * OUT_F + bcol + wc * 64 + lrow;
    int ai = (mf >> 2) * 16 + (mf & 3) * 4;
#pragma unroll
    for (int r = 0; r < 4; ++r)
#pragma unroll
      for (int nf = 0; nf < 4; ++nf)
        yp[(size_t)r * OUT_F + nf * 16] = acc[ai + nf][r];
  }
#undef STAGE_A
#undef STAGE_B
#undef MM
#undef BURST
}

// ---------------- 4) fwht2 (in-place on d_out) + SV + bias ----------------
__global__ __launch_bounds__(256) void fwht2_kernel(float* __restrict__ Y,
                                                    const float* __restrict__ SV,
                                                    const float* __restrict__ bias) {
  __shared__ float buf[4096];
  int tid = threadIdx.x;
  size_t rbase = (size_t)blockIdx.x * OUT_F;
  f32x4* y4 = (f32x4*)(Y + rbase);
  f32x4* b4 = (f32x4*)buf;
#pragma unroll
  for (int s = 0; s < 4; ++s) {
    int c = tid + 256 * s;
    b4[c] = y4[c];
  }
  __syncthreads();
  float v[16];
  {
#pragma unroll
    for (int j = 0; j < 4; ++j) {
      f32x4 t4 = b4[tid * 4 + j];
      v[j*4+0] = t4.x; v[j*4+1] = t4.y; v[j*4+2] = t4.z; v[j*4+3] = t4.w;
    }
    bfly16(v);
#pragma unroll
    for (int j = 0; j < 4; ++j) {
      f32x4 t4; t4.x = v[j*4+0]; t4.y = v[j*4+1]; t4.z = v[j*4+2]; t4.w = v[j*4+3];
      b4[tid * 4 + j] = t4;
    }
  }
  __syncthreads();
  {
    int lo = tid & 15, hi = tid >> 4;
    int base = lo + (hi << 8);
#pragma unroll
    for (int j = 0; j < 16; ++j) v[j] = buf[base + (j << 4)];
    bfly16(v);
#pragma unroll
    for (int j = 0; j < 16; ++j) buf[base + (j << 4)] = v[j];
  }
  __syncthreads();
  {
#pragma unroll
    for (int j = 0; j < 16; ++j) v[j] = buf[tid + (j << 8)];
    bfly16(v);
#pragma unroll
    for (int j = 0; j < 16; ++j) {
      int col = tid + (j << 8);
      Y[rbase + col] = v[j] * 0.015625f * SV[col] + bias[col];
    }
  }
}

extern "C" void kernel_launch(void* const* d_in, const int* in_sizes, int n_in,
                              void* d_out, int out_size, void* d_ws, size_t ws_size,
                              hipStream_t stream) {
  const float* x     = (const float*)d_in[0];
  const int*   Qidxs = (const int*)d_in[1];
  const float* grid  = (const float*)d_in[2];
  const float* SU    = (const float*)d_in[3];
  const float* SV    = (const float*)d_in[4];
  const float* bias  = (const float*)d_in[5];
  float* out = (float*)d_out;

  unsigned short* Wb = (unsigned short*)d_ws;                    // 4096*4096 bf16 = 33.5 MB
  unsigned short* Hb = Wb + (size_t)OUT_F * IN_F;                // 8192*4096 bf16 = 67 MB

  hipLaunchKernelGGL(dequant_kernel, dim3((OUT_F * (IN_F / 8)) / 256), dim3(256), 0, stream,
                     Qidxs, grid, Wb);
  hipLaunchKernelGGL(fwht1_kernel, dim3(NROWS), dim3(256), 0, stream, x, SU, Hb);
  hipLaunchKernelGGL(gemm256_kernel, dim3((NROWS / 256) * (OUT_F / 256)), dim3(512), 0, stream,
                     Hb, Wb, out);
  hipLaunchKernelGGL(fwht2_kernel, dim3(NROWS), dim3(256), 0, stream, out, SV, bias);
}